// Round 1
// baseline (1670.738 us; speedup 1.0000x reference)
//
#include <hip/hip_runtime.h>
#include <math.h>

#define NF 128          // feature dim F
#define FH 512          // FFN hidden
#define SQRT_DH 5.656854249492380f   // sqrt(32)
#define LN_EPS 1e-5f

// ---------------- Kernel 1: q/k projections -> ek = exp(s*k), qek = q*ek ---
// block = 128 threads (one per output column), 8 nodes per block
__global__ __launch_bounds__(128) void qk_kernel(
    const float* __restrict__ feat, const float* __restrict__ Wq,
    const float* __restrict__ Wk, float* __restrict__ ek,
    float* __restrict__ qek, int N)
{
    __shared__ float xs[8][NF];
    const int j  = threadIdx.x;
    const int n0 = blockIdx.x * 8;

    #pragma unroll
    for (int m = 0; m < 8; ++m) {
        int n = n0 + m;
        xs[m][j] = (n < N) ? feat[(size_t)n * NF + j] : 0.f;
    }
    __syncthreads();

    float aq[8] = {0}, ak[8] = {0};
    for (int k = 0; k < NF; ++k) {
        float wq = Wq[k * NF + j];
        float wk = Wk[k * NF + j];
        #pragma unroll
        for (int m = 0; m < 8; ++m) {
            aq[m] = fmaf(xs[m][k], wq, aq[m]);
            ak[m] = fmaf(xs[m][k], wk, ak[m]);
        }
    }

    #pragma unroll
    for (int m = 0; m < 8; ++m) {
        int n = n0 + m;
        if (n < N) {
            float e = __expf(SQRT_DH * ak[m]);
            ek [(size_t)n * NF + j] = e;
            qek[(size_t)n * NF + j] = aq[m] * e;
        }
    }
}

// ---------------- Kernel 2: edge scatter-add ------------------------------
// 64 threads per edge, each thread handles 2 channels (float2)
__global__ __launch_bounds__(256) void edge_kernel(
    const int* __restrict__ src, const int* __restrict__ dst,
    const float* __restrict__ ek, const float* __restrict__ qek,
    float* __restrict__ den, float* __restrict__ num, int E)
{
    int gid = blockIdx.x * 256 + threadIdx.x;
    int e   = gid >> 6;
    if (e >= E) return;
    int c2 = (gid & 63) << 1;

    int s = src[e];
    int d = dst[e];

    const float2 ev = *(const float2*)(ek  + (size_t)s * NF + c2);
    const float2 qv = *(const float2*)(qek + (size_t)s * NF + c2);

    float* dp = den + (size_t)d * NF + c2;
    float* np = num + (size_t)d * NF + c2;
    unsafeAtomicAdd(dp,     ev.x);
    unsafeAtomicAdd(dp + 1, ev.y);
    unsafeAtomicAdd(np,     qv.x);
    unsafeAtomicAdd(np + 1, qv.y);
}

// ---------------- Kernel 3: per-node epilogue -----------------------------
// agg = num/den; x = LN(agg + feat); h = PReLU(x@W1+b1); ffn = h@W2+b2;
// out = LN(x + ffn).   block = 128 threads, 8 nodes per block.
__global__ __launch_bounds__(128) void node_kernel(
    const float* __restrict__ feat, const float* __restrict__ num,
    const float* __restrict__ den, const float* __restrict__ ln_g,
    const float* __restrict__ ln_b, const float* __restrict__ W1,
    const float* __restrict__ b1, const float* __restrict__ alpha,
    const float* __restrict__ W2, const float* __restrict__ b2,
    float* __restrict__ out, int N)
{
    __shared__ float x[8][NF];
    __shared__ float h[8][FH];
    __shared__ float sred[2][2];

    const int tid  = threadIdx.x;
    const int lane = tid & 63;
    const int wv   = tid >> 6;
    const int n0   = blockIdx.x * 8;

    const float gg = ln_g[tid];
    const float bb = ln_b[tid];

    // ---- step 1: agg + residual + LayerNorm1 -> x in LDS
    for (int m = 0; m < 8; ++m) {
        int n = n0 + m;
        float xr = 0.f;
        if (n < N) {
            size_t off = (size_t)n * NF + tid;
            float dn = den[off];
            float ag = (dn > 0.f) ? num[off] / dn : 0.f;
            xr = ag + feat[off];
        }
        float s1 = xr, s2 = xr * xr;
        #pragma unroll
        for (int o = 32; o > 0; o >>= 1) {
            s1 += __shfl_down(s1, o);
            s2 += __shfl_down(s2, o);
        }
        if (lane == 0) { sred[0][wv] = s1; sred[1][wv] = s2; }
        __syncthreads();
        float mean = (sred[0][0] + sred[0][1]) * (1.f / NF);
        float msq  = (sred[1][0] + sred[1][1]) * (1.f / NF);
        float rs   = rsqrtf(msq - mean * mean + LN_EPS);
        x[m][tid] = (xr - mean) * rs * gg + bb;
        __syncthreads();
    }

    // ---- step 2: h = PReLU(x @ W1 + b1), 4 hidden cols per thread
    float acc[4][8];
    #pragma unroll
    for (int p = 0; p < 4; ++p)
        #pragma unroll
        for (int m = 0; m < 8; ++m) acc[p][m] = 0.f;

    for (int k = 0; k < NF; ++k) {
        float w[4];
        #pragma unroll
        for (int p = 0; p < 4; ++p) w[p] = W1[k * FH + tid + p * NF];
        #pragma unroll
        for (int m = 0; m < 8; ++m) {
            float xv = x[m][k];
            #pragma unroll
            for (int p = 0; p < 4; ++p) acc[p][m] = fmaf(xv, w[p], acc[p][m]);
        }
    }
    #pragma unroll
    for (int p = 0; p < 4; ++p) {
        int j = tid + p * NF;
        float bj = b1[j], aj = alpha[j];
        #pragma unroll
        for (int m = 0; m < 8; ++m) {
            float hv = acc[p][m] + bj;
            h[m][j] = (hv > 0.f) ? hv : aj * hv;
        }
    }
    __syncthreads();

    // ---- step 3: ffn = h @ W2 + b2; y = x + ffn; LayerNorm2 -> out
    float fac[8] = {0};
    for (int jj = 0; jj < FH; ++jj) {
        float w2v = W2[jj * NF + tid];
        #pragma unroll
        for (int m = 0; m < 8; ++m) fac[m] = fmaf(h[m][jj], w2v, fac[m]);
    }

    const float b2v = b2[tid];
    for (int m = 0; m < 8; ++m) {
        int n = n0 + m;
        float y = x[m][tid] + fac[m] + b2v;
        float s1 = y, s2 = y * y;
        #pragma unroll
        for (int o = 32; o > 0; o >>= 1) {
            s1 += __shfl_down(s1, o);
            s2 += __shfl_down(s2, o);
        }
        if (lane == 0) { sred[0][wv] = s1; sred[1][wv] = s2; }
        __syncthreads();
        float mean = (sred[0][0] + sred[0][1]) * (1.f / NF);
        float msq  = (sred[1][0] + sred[1][1]) * (1.f / NF);
        float rs   = rsqrtf(msq - mean * mean + LN_EPS);
        if (n < N) out[(size_t)n * NF + tid] = (y - mean) * rs * gg + bb;
        __syncthreads();
    }
}

// ---------------------------------------------------------------------------
extern "C" void kernel_launch(void* const* d_in, const int* in_sizes, int n_in,
                              void* d_out, int out_size, void* d_ws, size_t ws_size,
                              hipStream_t stream)
{
    const float* feat  = (const float*)d_in[0];
    const float* Wq    = (const float*)d_in[1];
    const float* Wk    = (const float*)d_in[2];
    // d_in[3] = Wv — mathematically cancels in edge softmax, unused.
    const float* ln_g  = (const float*)d_in[4];
    const float* ln_b  = (const float*)d_in[5];
    const float* W1    = (const float*)d_in[6];
    const float* b1    = (const float*)d_in[7];
    const float* alpha = (const float*)d_in[8];
    const float* W2    = (const float*)d_in[9];
    const float* b2    = (const float*)d_in[10];
    const int*   src   = (const int*)d_in[11];
    const int*   dst   = (const int*)d_in[12];

    const int N = in_sizes[0] / NF;
    const int E = in_sizes[11];
    float* out = (float*)d_out;

    float* ek  = (float*)d_ws;
    float* qek = ek  + (size_t)N * NF;
    float* den = qek + (size_t)N * NF;
    float* num = den + (size_t)N * NF;

    // zero the accumulators (den & num are adjacent)
    hipMemsetAsync(den, 0, (size_t)N * NF * 2 * sizeof(float), stream);

    qk_kernel<<<(N + 7) / 8, 128, 0, stream>>>(feat, Wq, Wk, ek, qek, N);

    int eThreads = E * 64;
    edge_kernel<<<(eThreads + 255) / 256, 256, 0, stream>>>(src, dst, ek, qek,
                                                            den, num, E);

    node_kernel<<<(N + 7) / 8, 128, 0, stream>>>(feat, num, den, ln_g, ln_b,
                                                 W1, b1, alpha, W2, b2, out, N);
}

// Round 2
// 605.412 us; speedup vs baseline: 2.7597x; 2.7597x over previous
//
#include <hip/hip_runtime.h>
#include <math.h>

#define NF 128          // feature dim F
#define FH 512          // FFN hidden
#define SQRT_DH 5.656854249492380f   // sqrt(32)
#define LN_EPS 1e-5f

// ---------------- Kernel 1: q/k projections -> kq = (exp(s*k), q*exp(s*k)) --
// block = 128 threads (one per output column), 8 nodes per block
__global__ __launch_bounds__(128) void qk_kernel(
    const float* __restrict__ feat, const float* __restrict__ Wq,
    const float* __restrict__ Wk, float2* __restrict__ kq, int N)
{
    __shared__ float xs[8][NF];
    const int j  = threadIdx.x;
    const int n0 = blockIdx.x * 8;

    #pragma unroll
    for (int m = 0; m < 8; ++m) {
        int n = n0 + m;
        xs[m][j] = (n < N) ? feat[(size_t)n * NF + j] : 0.f;
    }
    __syncthreads();

    float aq[8] = {0}, ak[8] = {0};
    for (int k = 0; k < NF; ++k) {
        float wq = Wq[k * NF + j];
        float wk = Wk[k * NF + j];
        #pragma unroll
        for (int m = 0; m < 8; ++m) {
            aq[m] = fmaf(xs[m][k], wq, aq[m]);
            ak[m] = fmaf(xs[m][k], wk, ak[m]);
        }
    }

    #pragma unroll
    for (int m = 0; m < 8; ++m) {
        int n = n0 + m;
        if (n < N) {
            float e = __expf(SQRT_DH * ak[m]);
            kq[(size_t)n * NF + j] = make_float2(e, aq[m] * e);
        }
    }
}

// ---------------- CSR build ------------------------------------------------
__global__ __launch_bounds__(256) void hist_kernel(
    const int* __restrict__ dst, int* __restrict__ deg, int E)
{
    int i = blockIdx.x * 256 + threadIdx.x;
    if (i < E) atomicAdd(&deg[dst[i]], 1);
}

// single-block exclusive scan: deg[0..N) -> off[0..N], cursor = off
__global__ __launch_bounds__(1024) void scan_kernel(
    const int* __restrict__ deg, int* __restrict__ off,
    int* __restrict__ cursor, int N)
{
    __shared__ int wsum[16];
    __shared__ int carry_s;
    const int tid = threadIdx.x;
    const int lane = tid & 63, w = tid >> 6;
    if (tid == 0) carry_s = 0;
    __syncthreads();

    for (int base = 0; base < N; base += 1024) {
        int i = base + tid;
        int v = (i < N) ? deg[i] : 0;
        int x = v;
        #pragma unroll
        for (int o = 1; o < 64; o <<= 1) {
            int t = __shfl_up(x, o);
            if (lane >= o) x += t;
        }
        if (lane == 63) wsum[w] = x;
        __syncthreads();
        if (w == 0 && lane < 16) {
            int s = wsum[lane];
            #pragma unroll
            for (int o = 1; o < 16; o <<= 1) {
                int t = __shfl_up(s, o);
                if (lane >= o) s += t;
            }
            wsum[lane] = s;
        }
        __syncthreads();
        int wbase = (w == 0) ? 0 : wsum[w - 1];
        int carry = carry_s;
        int incl  = carry + wbase + x;
        if (i < N) { int ex = incl - v; off[i] = ex; cursor[i] = ex; }
        __syncthreads();
        if (tid == 1023) carry_s = incl;
        __syncthreads();
    }
    if (tid == 0) off[N] = carry_s;
}

__global__ __launch_bounds__(256) void scatter_kernel(
    const int* __restrict__ src, const int* __restrict__ dst,
    int* __restrict__ cursor, int* __restrict__ col, int E)
{
    int i = blockIdx.x * 256 + threadIdx.x;
    if (i < E) {
        int pos = atomicAdd(&cursor[dst[i]], 1);
        col[pos] = src[i];
    }
}

// ---------------- Kernel 3: fused gather + epilogue ------------------------
// agg = num/den via CSR gather; x = LN(agg + feat); h = PReLU(x@W1+b1);
// ffn = h@W2+b2; out = LN(x + ffn).  block = 128 threads, 8 nodes per block.
__global__ __launch_bounds__(128) void node_kernel(
    const float* __restrict__ feat, const float2* __restrict__ kq,
    const int* __restrict__ off, const int* __restrict__ col,
    const float* __restrict__ ln_g, const float* __restrict__ ln_b,
    const float* __restrict__ W1, const float* __restrict__ b1,
    const float* __restrict__ alpha, const float* __restrict__ W2,
    const float* __restrict__ b2, float* __restrict__ out, int N)
{
    __shared__ float x[8][NF];
    __shared__ float h[8][FH];
    __shared__ float sred[2][2];

    const int tid  = threadIdx.x;
    const int lane = tid & 63;
    const int wv   = tid >> 6;
    const int n0   = blockIdx.x * 8;

    const float gg = ln_g[tid];
    const float bb = ln_b[tid];

    // ---- step 1: CSR gather -> agg, + residual + LayerNorm1 -> x in LDS
    for (int m = 0; m < 8; ++m) {
        int n = n0 + m;
        float xr = 0.f;
        if (n < N) {
            int e0 = off[n], e1 = off[n + 1];
            float d0 = 0.f, q0 = 0.f, d1 = 0.f, q1 = 0.f;
            int e = e0;
            for (; e + 1 < e1; e += 2) {
                int s0 = col[e], s1 = col[e + 1];
                float2 v0 = kq[(size_t)s0 * NF + tid];
                float2 v1 = kq[(size_t)s1 * NF + tid];
                d0 += v0.x; q0 += v0.y;
                d1 += v1.x; q1 += v1.y;
            }
            if (e < e1) {
                float2 v = kq[(size_t)col[e] * NF + tid];
                d0 += v.x; q0 += v.y;
            }
            d0 += d1; q0 += q1;
            float ag = (e1 > e0) ? q0 / d0 : 0.f;
            xr = ag + feat[(size_t)n * NF + tid];
        }
        float s1v = xr, s2v = xr * xr;
        #pragma unroll
        for (int o = 32; o > 0; o >>= 1) {
            s1v += __shfl_down(s1v, o);
            s2v += __shfl_down(s2v, o);
        }
        if (lane == 0) { sred[0][wv] = s1v; sred[1][wv] = s2v; }
        __syncthreads();
        float mean = (sred[0][0] + sred[0][1]) * (1.f / NF);
        float msq  = (sred[1][0] + sred[1][1]) * (1.f / NF);
        float rs   = rsqrtf(msq - mean * mean + LN_EPS);
        x[m][tid] = (xr - mean) * rs * gg + bb;
        __syncthreads();
    }

    // ---- step 2: h = PReLU(x @ W1 + b1), 4 hidden cols per thread
    float acc[4][8];
    #pragma unroll
    for (int p = 0; p < 4; ++p)
        #pragma unroll
        for (int m = 0; m < 8; ++m) acc[p][m] = 0.f;

    for (int k = 0; k < NF; ++k) {
        float w[4];
        #pragma unroll
        for (int p = 0; p < 4; ++p) w[p] = W1[k * FH + tid + p * NF];
        #pragma unroll
        for (int m = 0; m < 8; ++m) {
            float xv = x[m][k];
            #pragma unroll
            for (int p = 0; p < 4; ++p) acc[p][m] = fmaf(xv, w[p], acc[p][m]);
        }
    }
    #pragma unroll
    for (int p = 0; p < 4; ++p) {
        int j = tid + p * NF;
        float bj = b1[j], aj = alpha[j];
        #pragma unroll
        for (int m = 0; m < 8; ++m) {
            float hv = acc[p][m] + bj;
            h[m][j] = (hv > 0.f) ? hv : aj * hv;
        }
    }
    __syncthreads();

    // ---- step 3: ffn = h @ W2 + b2; y = x + ffn; LayerNorm2 -> out
    float fac[8] = {0};
    for (int jj = 0; jj < FH; ++jj) {
        float w2v = W2[jj * NF + tid];
        #pragma unroll
        for (int m = 0; m < 8; ++m) fac[m] = fmaf(h[m][jj], w2v, fac[m]);
    }

    const float b2v = b2[tid];
    for (int m = 0; m < 8; ++m) {
        int n = n0 + m;
        float y = x[m][tid] + fac[m] + b2v;
        float s1v = y, s2v = y * y;
        #pragma unroll
        for (int o = 32; o > 0; o >>= 1) {
            s1v += __shfl_down(s1v, o);
            s2v += __shfl_down(s2v, o);
        }
        if (lane == 0) { sred[0][wv] = s1v; sred[1][wv] = s2v; }
        __syncthreads();
        float mean = (sred[0][0] + sred[0][1]) * (1.f / NF);
        float msq  = (sred[1][0] + sred[1][1]) * (1.f / NF);
        float rs   = rsqrtf(msq - mean * mean + LN_EPS);
        if (n < N) out[(size_t)n * NF + tid] = (y - mean) * rs * gg + bb;
        __syncthreads();
    }
}

// ---------------------------------------------------------------------------
extern "C" void kernel_launch(void* const* d_in, const int* in_sizes, int n_in,
                              void* d_out, int out_size, void* d_ws, size_t ws_size,
                              hipStream_t stream)
{
    const float* feat  = (const float*)d_in[0];
    const float* Wq    = (const float*)d_in[1];
    const float* Wk    = (const float*)d_in[2];
    // d_in[3] = Wv — cancels in per-channel edge softmax, unused.
    const float* ln_g  = (const float*)d_in[4];
    const float* ln_b  = (const float*)d_in[5];
    const float* W1    = (const float*)d_in[6];
    const float* b1    = (const float*)d_in[7];
    const float* alpha = (const float*)d_in[8];
    const float* W2    = (const float*)d_in[9];
    const float* b2    = (const float*)d_in[10];
    const int*   src   = (const int*)d_in[11];
    const int*   dst   = (const int*)d_in[12];

    const int N = in_sizes[0] / NF;
    const int E = in_sizes[11];
    float* out = (float*)d_out;

    // workspace layout (float2 array first for 8B alignment)
    float2* kq     = (float2*)d_ws;
    int*    deg    = (int*)(kq + (size_t)N * NF);
    int*    off    = deg + N;            // N+1 entries
    int*    cursor = off + (N + 1);
    int*    col    = cursor + N;         // E entries

    hipMemsetAsync(deg, 0, (size_t)N * sizeof(int), stream);

    qk_kernel<<<(N + 7) / 8, 128, 0, stream>>>(feat, Wq, Wk, kq, N);
    hist_kernel<<<(E + 255) / 256, 256, 0, stream>>>(dst, deg, E);
    scan_kernel<<<1, 1024, 0, stream>>>(deg, off, cursor, N);
    scatter_kernel<<<(E + 255) / 256, 256, 0, stream>>>(src, dst, cursor, col, E);
    node_kernel<<<(N + 7) / 8, 128, 0, stream>>>(feat, kq, off, col, ln_g, ln_b,
                                                 W1, b1, alpha, W2, b2, out, N);
}

// Round 3
// 307.723 us; speedup vs baseline: 5.4294x; 1.9674x over previous
//
#include <hip/hip_runtime.h>
#include <math.h>

#define NF 128
#define FH 512
#define SQRT_DH 5.656854249492380f
#define LN_EPS 1e-5f

typedef __attribute__((ext_vector_type(8))) short short8;
typedef __attribute__((ext_vector_type(4))) float f32x4;

__device__ __forceinline__ unsigned short f2bf(float x) {
    union { float f; unsigned u; } c; c.f = x;
    unsigned u = c.u;
    return (unsigned short)((u + 0x7fffu + ((u >> 16) & 1u)) >> 16);
}
__device__ __forceinline__ float lo_bf(unsigned u) {
    union { unsigned u; float f; } c; c.u = u << 16; return c.f;
}
__device__ __forceinline__ float hi_bf(unsigned u) {
    union { unsigned u; float f; } c; c.u = u & 0xffff0000u; return c.f;
}

// ---------------- Kernel 1: q/k projections -> kq = pack(bf16(ek), bf16(q*ek))
__global__ __launch_bounds__(128) void qk_kernel(
    const float* __restrict__ feat, const float* __restrict__ Wq,
    const float* __restrict__ Wk, unsigned* __restrict__ kq, int N)
{
    __shared__ float xs[8][NF];
    const int j  = threadIdx.x;
    const int n0 = blockIdx.x * 8;

    #pragma unroll
    for (int m = 0; m < 8; ++m) {
        int n = n0 + m;
        xs[m][j] = (n < N) ? feat[(size_t)n * NF + j] : 0.f;
    }
    __syncthreads();

    float aq[8] = {0}, ak[8] = {0};
    for (int k = 0; k < NF; ++k) {
        float wq = Wq[k * NF + j];
        float wk = Wk[k * NF + j];
        #pragma unroll
        for (int m = 0; m < 8; ++m) {
            aq[m] = fmaf(xs[m][k], wq, aq[m]);
            ak[m] = fmaf(xs[m][k], wk, ak[m]);
        }
    }

    #pragma unroll
    for (int m = 0; m < 8; ++m) {
        int n = n0 + m;
        if (n < N) {
            float e = __expf(SQRT_DH * ak[m]);
            unsigned pk = ((unsigned)f2bf(aq[m] * e) << 16) | (unsigned)f2bf(e);
            kq[(size_t)n * NF + j] = pk;
        }
    }
}

// ---------------- weight prep: fp32 -> bf16 in MFMA B-fragment order --------
// W1f[kt][ntg][lane][i] = W1[kt*32 + (lane>>4)*8 + i][ntg*16 + (lane&15)]
// W2f[kt2][nt2][lane][i] = W2[kt2*32 + (lane>>4)*8 + i][nt2*16 + (lane&15)]
__global__ __launch_bounds__(256) void prep_w(
    const float* __restrict__ W1, const float* __restrict__ W2,
    unsigned short* __restrict__ W1f, unsigned short* __restrict__ W2f)
{
    int f = blockIdx.x * 256 + threadIdx.x;   // 0..65535
    int i = f & 7, l = (f >> 3) & 63;
    int lg = l >> 4, l15 = l & 15;
    {
        int ntg = (f >> 9) & 31, kt = f >> 14;
        int k = kt * 32 + lg * 8 + i, n = ntg * 16 + l15;
        W1f[f] = f2bf(W1[k * FH + n]);
    }
    {
        int nt2 = (f >> 9) & 7, kt2 = f >> 12;
        int k = kt2 * 32 + lg * 8 + i, n = nt2 * 16 + l15;
        W2f[f] = f2bf(W2[k * NF + n]);
    }
}

// ---------------- CSR build ------------------------------------------------
__global__ __launch_bounds__(256) void hist_kernel(
    const int* __restrict__ dst, int* __restrict__ deg, int E)
{
    int i = blockIdx.x * 256 + threadIdx.x;
    if (i < E) atomicAdd(&deg[dst[i]], 1);
}

__global__ __launch_bounds__(1024) void scan_blk(
    const int* __restrict__ deg, int* __restrict__ off,
    int* __restrict__ bsum, int N)
{
    __shared__ int ws[16];
    const int tid = threadIdx.x, lane = tid & 63, w = tid >> 6;
    int i = blockIdx.x * 1024 + tid;
    int v = (i < N) ? deg[i] : 0;
    int x = v;
    #pragma unroll
    for (int o = 1; o < 64; o <<= 1) {
        int t = __shfl_up(x, o);
        if (lane >= o) x += t;
    }
    if (lane == 63) ws[w] = x;
    __syncthreads();
    if (w == 0 && lane < 16) {
        int s = ws[lane];
        #pragma unroll
        for (int o = 1; o < 16; o <<= 1) {
            int t = __shfl_up(s, o);
            if (lane >= o) s += t;
        }
        ws[lane] = s;
    }
    __syncthreads();
    int wbase = (w == 0) ? 0 : ws[w - 1];
    int incl = wbase + x;
    if (i < N) off[i] = incl - v;           // exclusive within block
    if (tid == 1023) bsum[blockIdx.x] = incl;
}

__global__ __launch_bounds__(64) void scan_mid(int* __restrict__ bsum, int nb)
{
    int lane = threadIdx.x;
    int v = (lane < nb) ? bsum[lane] : 0;
    int x = v;
    #pragma unroll
    for (int o = 1; o < 64; o <<= 1) {
        int t = __shfl_up(x, o);
        if (lane >= o) x += t;
    }
    if (lane < nb) bsum[lane] = x - v;       // exclusive block base
}

__global__ __launch_bounds__(1024) void scan_add(
    int* __restrict__ off, int* __restrict__ cursor,
    const int* __restrict__ bsum, int N, int E)
{
    int i = blockIdx.x * 1024 + threadIdx.x;
    if (i < N) {
        int o = off[i] + bsum[blockIdx.x];
        off[i] = o; cursor[i] = o;
    }
    if (i == 0) off[N] = E;
}

__global__ __launch_bounds__(256) void scatter_kernel(
    const int* __restrict__ src, const int* __restrict__ dst,
    int* __restrict__ cursor, int* __restrict__ col, int E)
{
    int i = blockIdx.x * 256 + threadIdx.x;
    if (i < E) {
        int pos = atomicAdd(&cursor[dst[i]], 1);
        col[pos] = src[i];
    }
}

// ---------------- gather + residual + LN1 -> xb (bf16), xf (fp32) ----------
__global__ __launch_bounds__(128) void gather_ln1(
    const float* __restrict__ feat, const unsigned* __restrict__ kq,
    const int* __restrict__ off, const int* __restrict__ col,
    const float* __restrict__ ln_g, const float* __restrict__ ln_b,
    unsigned short* __restrict__ xb, float* __restrict__ xf, int N)
{
    __shared__ float sred[2][2];
    const int tid = threadIdx.x;
    const int lane = tid & 63;
    const int wv = tid >> 6;
    const int n0 = blockIdx.x * 8;

    const float gg = ln_g[tid];
    const float bb = ln_b[tid];

    for (int m = 0; m < 8; ++m) {
        int n = n0 + m;
        float xr = 0.f;
        if (n < N) {
            int e0 = off[n], e1 = off[n + 1];
            float d0 = 0.f, q0 = 0.f, d1 = 0.f, q1 = 0.f;
            int e = e0;
            for (; e + 1 < e1; e += 2) {
                unsigned u0 = kq[(size_t)col[e]     * NF + tid];
                unsigned u1 = kq[(size_t)col[e + 1] * NF + tid];
                d0 += lo_bf(u0); q0 += hi_bf(u0);
                d1 += lo_bf(u1); q1 += hi_bf(u1);
            }
            if (e < e1) {
                unsigned u = kq[(size_t)col[e] * NF + tid];
                d0 += lo_bf(u); q0 += hi_bf(u);
            }
            d0 += d1; q0 += q1;
            float ag = (e1 > e0) ? q0 / d0 : 0.f;
            xr = ag + feat[(size_t)n * NF + tid];
        }
        float s1 = xr, s2 = xr * xr;
        #pragma unroll
        for (int o = 32; o > 0; o >>= 1) {
            s1 += __shfl_down(s1, o);
            s2 += __shfl_down(s2, o);
        }
        if (lane == 0) { sred[0][wv] = s1; sred[1][wv] = s2; }
        __syncthreads();
        float mean = (sred[0][0] + sred[0][1]) * (1.f / NF);
        float msq  = (sred[1][0] + sred[1][1]) * (1.f / NF);
        float rs   = rsqrtf(msq - mean * mean + LN_EPS);
        float xv   = (xr - mean) * rs * gg + bb;
        if (n < N) {
            xb[(size_t)n * NF + tid] = f2bf(xv);
            xf[(size_t)n * NF + tid] = xv;
        }
        __syncthreads();
    }
}

// ---------------- fused FFN: GEMM1(MFMA)+PReLU -> GEMM2(MFMA) -> LN2 -------
// block = 256 threads (4 waves), BM = 32 nodes.
// GEMM1: waves split N (FH=512 -> 128 cols each); GEMM2: waves split K.
__global__ __launch_bounds__(256) void ffn_fused(
    const unsigned short* __restrict__ xb, const float* __restrict__ xf,
    const unsigned short* __restrict__ W1f, const unsigned short* __restrict__ W2f,
    const float* __restrict__ b1, const float* __restrict__ alpha,
    const float* __restrict__ W2b_unused, const float* __restrict__ b2,
    const float* __restrict__ ln_g, const float* __restrict__ ln_b,
    float* __restrict__ out, int N)
{
    __shared__ unsigned short hlds[4][32][128];  // 32 KB, per-wave slab, XOR-swizzled
    __shared__ float olds[32][NF + 4];           // 16.5 KB, padded vs bank conflicts

    const int tid = threadIdx.x;
    const int l = tid & 63;
    const int wid = tid >> 6;
    const int l15 = l & 15;
    const int lg = l >> 4;
    const int n0 = blockIdx.x * 32;

    char* hbase = (char*)&hlds[wid][0][0];

    // ---- GEMM1: acc[mf][nt] = x[mf-rows] @ W1[:, wid*128 + nt*16 ...]
    f32x4 acc[2][8];
    #pragma unroll
    for (int mf = 0; mf < 2; ++mf)
        #pragma unroll
        for (int nt = 0; nt < 8; ++nt)
            acc[mf][nt] = (f32x4){0.f, 0.f, 0.f, 0.f};

    #pragma unroll
    for (int kt = 0; kt < 4; ++kt) {
        short8 a0 = *(const short8*)(xb + (size_t)(n0 + l15)      * NF + kt * 32 + lg * 8);
        short8 a1 = *(const short8*)(xb + (size_t)(n0 + 16 + l15) * NF + kt * 32 + lg * 8);
        #pragma unroll
        for (int nt = 0; nt < 8; ++nt) {
            int ntg = wid * 8 + nt;
            short8 b = *(const short8*)(W1f + ((kt * 32 + ntg) * 64 + l) * 8);
            acc[0][nt] = __builtin_amdgcn_mfma_f32_16x16x32_bf16(a0, b, acc[0][nt], 0, 0, 0);
            acc[1][nt] = __builtin_amdgcn_mfma_f32_16x16x32_bf16(a1, b, acc[1][nt], 0, 0, 0);
        }
    }

    // epilogue: + b1, PReLU, -> hlds (swizzled bf16)
    #pragma unroll
    for (int nt = 0; nt < 8; ++nt) {
        int jloc = nt * 16 + l15;
        int j = wid * 128 + jloc;
        float b1j = b1[j], alj = alpha[j];
        #pragma unroll
        for (int mf = 0; mf < 2; ++mf) {
            #pragma unroll
            for (int r = 0; r < 4; ++r) {
                int row = mf * 16 + lg * 4 + r;
                float hv = acc[mf][nt][r] + b1j;
                hv = hv > 0.f ? hv : alj * hv;
                int byte = row * 256 + ((jloc * 2) ^ ((row & 7) << 4));
                *(unsigned short*)(hbase + byte) = f2bf(hv);
            }
        }
    }
    __syncthreads();

    // ---- GEMM2: partial over wave's K-slab (cols wid*128..+128 of h)
    f32x4 acc2[2][8];
    #pragma unroll
    for (int mf = 0; mf < 2; ++mf)
        #pragma unroll
        for (int nt = 0; nt < 8; ++nt)
            acc2[mf][nt] = (f32x4){0.f, 0.f, 0.f, 0.f};

    #pragma unroll
    for (int kt = 0; kt < 4; ++kt) {
        int row0 = l15, row1 = 16 + l15;
        int c0 = (kt * 64 + lg * 16) ^ ((row0 & 7) << 4);
        int c1 = (kt * 64 + lg * 16) ^ ((row1 & 7) << 4);
        short8 a0 = *(const short8*)(hbase + row0 * 256 + c0);
        short8 a1 = *(const short8*)(hbase + row1 * 256 + c1);
        int kt2g = wid * 4 + kt;
        #pragma unroll
        for (int nt = 0; nt < 8; ++nt) {
            short8 b = *(const short8*)(W2f + ((kt2g * 8 + nt) * 64 + l) * 8);
            acc2[0][nt] = __builtin_amdgcn_mfma_f32_16x16x32_bf16(a0, b, acc2[0][nt], 0, 0, 0);
            acc2[1][nt] = __builtin_amdgcn_mfma_f32_16x16x32_bf16(a1, b, acc2[1][nt], 0, 0, 0);
        }
    }

    // ---- cross-wave K reduction into olds
    for (int w = 0; w < 4; ++w) {
        if (wid == w) {
            #pragma unroll
            for (int nt = 0; nt < 8; ++nt) {
                int cl = nt * 16 + l15;
                #pragma unroll
                for (int mf = 0; mf < 2; ++mf) {
                    #pragma unroll
                    for (int r = 0; r < 4; ++r) {
                        int row = mf * 16 + lg * 4 + r;
                        if (w == 0) olds[row][cl]  = acc2[mf][nt][r];
                        else        olds[row][cl] += acc2[mf][nt][r];
                    }
                }
            }
        }
        __syncthreads();
    }

    // ---- LN2: one row per wave per iter (64 lanes x 2 cols), no barriers
    const float gg0 = ln_g[l], gg1 = ln_g[l + 64];
    const float bb0 = ln_b[l], bb1 = ln_b[l + 64];
    const float b20 = b2[l],   b21 = b2[l + 64];
    #pragma unroll
    for (int rr = 0; rr < 8; ++rr) {
        int row = rr * 4 + wid;
        int n = n0 + row;
        float y0 = 0.f, y1 = 0.f;
        if (n < N) {
            y0 = xf[(size_t)n * NF + l]      + olds[row][l]      + b20;
            y1 = xf[(size_t)n * NF + l + 64] + olds[row][l + 64] + b21;
        }
        float s1 = y0 + y1, s2 = y0 * y0 + y1 * y1;
        #pragma unroll
        for (int o = 32; o > 0; o >>= 1) {
            s1 += __shfl_xor(s1, o);
            s2 += __shfl_xor(s2, o);
        }
        float mean = s1 * (1.f / NF);
        float msq  = s2 * (1.f / NF);
        float rs   = rsqrtf(msq - mean * mean + LN_EPS);
        if (n < N) {
            out[(size_t)n * NF + l]      = (y0 - mean) * rs * gg0 + bb0;
            out[(size_t)n * NF + l + 64] = (y1 - mean) * rs * gg1 + bb1;
        }
    }
}

// ---------------------------------------------------------------------------
extern "C" void kernel_launch(void* const* d_in, const int* in_sizes, int n_in,
                              void* d_out, int out_size, void* d_ws, size_t ws_size,
                              hipStream_t stream)
{
    const float* feat  = (const float*)d_in[0];
    const float* Wq    = (const float*)d_in[1];
    const float* Wk    = (const float*)d_in[2];
    // d_in[3] = Wv — cancels in per-channel edge softmax, unused.
    const float* ln_g  = (const float*)d_in[4];
    const float* ln_b  = (const float*)d_in[5];
    const float* W1    = (const float*)d_in[6];
    const float* b1    = (const float*)d_in[7];
    const float* alpha = (const float*)d_in[8];
    const float* W2    = (const float*)d_in[9];
    const float* b2    = (const float*)d_in[10];
    const int*   src   = (const int*)d_in[11];
    const int*   dst   = (const int*)d_in[12];

    const int N = in_sizes[0] / NF;
    const int E = in_sizes[11];
    const int Npad = ((N + 31) / 32) * 32;
    float* out = (float*)d_out;

    // workspace layout (16B-aligned chunks)
    char* p = (char*)d_ws;
    unsigned*       kq  = (unsigned*)p;       p += (size_t)N * NF * 4;
    unsigned short* xb  = (unsigned short*)p; p += (size_t)Npad * NF * 2;
    float*          xf  = (float*)p;          p += (size_t)Npad * NF * 4;
    unsigned short* W1f = (unsigned short*)p; p += (size_t)NF * FH * 2;
    unsigned short* W2f = (unsigned short*)p; p += (size_t)FH * NF * 2;
    int* deg    = (int*)p;  p += (size_t)N * 4;
    int* off    = (int*)p;  p += (size_t)(N + 1) * 4;
    int* bsum   = (int*)p;  p += 64 * 4;
    int* cursor = (int*)p;  p += (size_t)N * 4;
    int* col    = (int*)p;

    const int nb = (N + 1023) / 1024;

    hipMemsetAsync(deg, 0, (size_t)N * sizeof(int), stream);

    prep_w<<<256, 256, 0, stream>>>(W1, W2, W1f, W2f);
    qk_kernel<<<(N + 7) / 8, 128, 0, stream>>>(feat, Wq, Wk, kq, N);
    hist_kernel<<<(E + 255) / 256, 256, 0, stream>>>(dst, deg, E);
    scan_blk<<<nb, 1024, 0, stream>>>(deg, off, bsum, N);
    scan_mid<<<1, 64, 0, stream>>>(bsum, nb);
    scan_add<<<nb, 1024, 0, stream>>>(off, cursor, bsum, N, E);
    scatter_kernel<<<(E + 255) / 256, 256, 0, stream>>>(src, dst, cursor, col, E);
    gather_ln1<<<(N + 7) / 8, 128, 0, stream>>>(feat, kq, off, col, ln_g, ln_b,
                                                xb, xf, N);
    ffn_fused<<<(N + 31) / 32, 256, 0, stream>>>(xb, xf, W1f, W2f, b1, alpha,
                                                 nullptr, b2, ln_g, ln_b, out, N);
}

// Round 4
// 261.245 us; speedup vs baseline: 6.3953x; 1.1779x over previous
//
#include <hip/hip_runtime.h>
#include <math.h>

#define NF 128
#define FH 512
#define SQRT_DH 5.656854249492380f
#define LN_EPS 1e-5f

typedef __attribute__((ext_vector_type(8))) short short8;
typedef __attribute__((ext_vector_type(4))) float f32x4;

__device__ __forceinline__ unsigned short f2bf(float x) {
    union { float f; unsigned u; } c; c.f = x;
    unsigned u = c.u;
    return (unsigned short)((u + 0x7fffu + ((u >> 16) & 1u)) >> 16);
}
__device__ __forceinline__ float bf2f(unsigned short h) {
    union { unsigned u; float f; } c; c.u = (unsigned)h << 16; return c.f;
}
__device__ __forceinline__ float lo_bf(unsigned u) {
    union { unsigned u; float f; } c; c.u = u << 16; return c.f;
}
__device__ __forceinline__ float hi_bf(unsigned u) {
    union { unsigned u; float f; } c; c.u = u & 0xffff0000u; return c.f;
}

// ---------------- weight prep ------------------------------------------------
// B-fragment order (verified by round-3 pass): frag[kt][nt][lane][i] =
//   W[kt*32 + (lane>>4)*8 + i][nt*16 + (lane&15)]
// W1f: 128x512 (32 nt), W2f: 512x128 (8 nt, 16 kt), Wq/Wk: 128x128 hi+lo.
__global__ __launch_bounds__(256) void prep_w(
    const float* __restrict__ W1, const float* __restrict__ W2,
    const float* __restrict__ Wq, const float* __restrict__ Wk,
    unsigned short* __restrict__ W1f, unsigned short* __restrict__ W2f,
    unsigned short* __restrict__ Wqhi, unsigned short* __restrict__ Wqlo,
    unsigned short* __restrict__ Wkhi, unsigned short* __restrict__ Wklo)
{
    int f = blockIdx.x * 256 + threadIdx.x;   // 0..65535
    int i = f & 7, l = (f >> 3) & 63;
    int lg = l >> 4, l15 = l & 15;
    {
        int ntg = (f >> 9) & 31, kt = f >> 14;
        int k = kt * 32 + lg * 8 + i, n = ntg * 16 + l15;
        W1f[f] = f2bf(W1[k * FH + n]);
    }
    {
        int nt2 = (f >> 9) & 7, kt2 = f >> 12;
        int k = kt2 * 32 + lg * 8 + i, n = nt2 * 16 + l15;
        W2f[f] = f2bf(W2[k * NF + n]);
    }
    if (f < 16384) {
        int nt = (f >> 9) & 7, kt = f >> 12;
        int k = kt * 32 + lg * 8 + i, n = nt * 16 + l15;
        float vq = Wq[k * NF + n];
        unsigned short qh = f2bf(vq);
        Wqhi[f] = qh; Wqlo[f] = f2bf(vq - bf2f(qh));
        float vk = Wk[k * NF + n];
        unsigned short kh = f2bf(vk);
        Wkhi[f] = kh; Wklo[f] = f2bf(vk - bf2f(kh));
    }
}

// ---------------- Kernel 1: q/k projections via MFMA (hi/lo split) ----------
// block = 256 thr (4 waves), BM = 32 nodes; wave wid owns cols wid*32..+32.
// k,q computed as hi@Whi + lo@Whi + hi@Wlo  (error ~2^-17, fp32-equivalent).
__global__ __launch_bounds__(256) void qk_mfma(
    const float* __restrict__ feat,
    const unsigned short* __restrict__ Wqhi, const unsigned short* __restrict__ Wqlo,
    const unsigned short* __restrict__ Wkhi, const unsigned short* __restrict__ Wklo,
    unsigned* __restrict__ kq, int N)
{
    const int tid = threadIdx.x;
    const int l = tid & 63, wid = tid >> 6;
    const int l15 = l & 15, lg = l >> 4;
    const int n0 = blockIdx.x * 32;

    f32x4 accq[2][2], acck[2][2];
    #pragma unroll
    for (int mf = 0; mf < 2; ++mf)
        #pragma unroll
        for (int nt = 0; nt < 2; ++nt) {
            accq[mf][nt] = (f32x4){0.f, 0.f, 0.f, 0.f};
            acck[mf][nt] = (f32x4){0.f, 0.f, 0.f, 0.f};
        }

    #pragma unroll
    for (int kt = 0; kt < 4; ++kt) {
        short8 ahi[2], alo[2];
        #pragma unroll
        for (int mf = 0; mf < 2; ++mf) {
            int n = n0 + mf * 16 + l15;
            float v[8];
            if (n < N) {
                const float4* p = (const float4*)(feat + (size_t)n * NF + kt * 32 + lg * 8);
                float4 v0 = p[0], v1 = p[1];
                v[0] = v0.x; v[1] = v0.y; v[2] = v0.z; v[3] = v0.w;
                v[4] = v1.x; v[5] = v1.y; v[6] = v1.z; v[7] = v1.w;
            } else {
                #pragma unroll
                for (int i = 0; i < 8; ++i) v[i] = 0.f;
            }
            #pragma unroll
            for (int i = 0; i < 8; ++i) {
                unsigned short h = f2bf(v[i]);
                ahi[mf][i] = (short)h;
                alo[mf][i] = (short)f2bf(v[i] - bf2f(h));
            }
        }
        #pragma unroll
        for (int nt = 0; nt < 2; ++nt) {
            int ntg = wid * 2 + nt;
            size_t fo = ((size_t)(kt * 8 + ntg) * 64 + l) * 8;
            short8 bqh = *(const short8*)(Wqhi + fo);
            short8 bql = *(const short8*)(Wqlo + fo);
            short8 bkh = *(const short8*)(Wkhi + fo);
            short8 bkl = *(const short8*)(Wklo + fo);
            #pragma unroll
            for (int mf = 0; mf < 2; ++mf) {
                accq[mf][nt] = __builtin_amdgcn_mfma_f32_16x16x32_bf16(ahi[mf], bqh, accq[mf][nt], 0, 0, 0);
                accq[mf][nt] = __builtin_amdgcn_mfma_f32_16x16x32_bf16(alo[mf], bqh, accq[mf][nt], 0, 0, 0);
                accq[mf][nt] = __builtin_amdgcn_mfma_f32_16x16x32_bf16(ahi[mf], bql, accq[mf][nt], 0, 0, 0);
                acck[mf][nt] = __builtin_amdgcn_mfma_f32_16x16x32_bf16(ahi[mf], bkh, acck[mf][nt], 0, 0, 0);
                acck[mf][nt] = __builtin_amdgcn_mfma_f32_16x16x32_bf16(alo[mf], bkh, acck[mf][nt], 0, 0, 0);
                acck[mf][nt] = __builtin_amdgcn_mfma_f32_16x16x32_bf16(ahi[mf], bkl, acck[mf][nt], 0, 0, 0);
            }
        }
    }

    // epilogue: ek = exp(s*k), pack(bf16(q*ek), bf16(ek)) -> kq
    #pragma unroll
    for (int mf = 0; mf < 2; ++mf) {
        #pragma unroll
        for (int nt = 0; nt < 2; ++nt) {
            int colg = wid * 32 + nt * 16 + l15;
            #pragma unroll
            for (int r = 0; r < 4; ++r) {
                int n = n0 + mf * 16 + lg * 4 + r;
                if (n < N) {
                    float kk = acck[mf][nt][r];
                    float qq = accq[mf][nt][r];
                    float e = __expf(SQRT_DH * kk);
                    kq[(size_t)n * NF + colg] =
                        ((unsigned)f2bf(qq * e) << 16) | (unsigned)f2bf(e);
                }
            }
        }
    }
}

// ---------------- CSR build ------------------------------------------------
__global__ __launch_bounds__(256) void hist_kernel(
    const int* __restrict__ dst, int* __restrict__ deg, int E)
{
    int i = blockIdx.x * 256 + threadIdx.x;
    if (i < E) atomicAdd(&deg[dst[i]], 1);
}

__global__ __launch_bounds__(1024) void scan_blk(
    const int* __restrict__ deg, int* __restrict__ off,
    int* __restrict__ bsum, int N)
{
    __shared__ int ws[16];
    const int tid = threadIdx.x, lane = tid & 63, w = tid >> 6;
    int i = blockIdx.x * 1024 + tid;
    int v = (i < N) ? deg[i] : 0;
    int x = v;
    #pragma unroll
    for (int o = 1; o < 64; o <<= 1) {
        int t = __shfl_up(x, o);
        if (lane >= o) x += t;
    }
    if (lane == 63) ws[w] = x;
    __syncthreads();
    if (w == 0 && lane < 16) {
        int s = ws[lane];
        #pragma unroll
        for (int o = 1; o < 16; o <<= 1) {
            int t = __shfl_up(s, o);
            if (lane >= o) s += t;
        }
        ws[lane] = s;
    }
    __syncthreads();
    int wbase = (w == 0) ? 0 : ws[w - 1];
    int incl = wbase + x;
    if (i < N) off[i] = incl - v;
    if (tid == 1023) bsum[blockIdx.x] = incl;
}

__global__ __launch_bounds__(64) void scan_mid(int* __restrict__ bsum, int nb)
{
    int lane = threadIdx.x;
    int v = (lane < nb) ? bsum[lane] : 0;
    int x = v;
    #pragma unroll
    for (int o = 1; o < 64; o <<= 1) {
        int t = __shfl_up(x, o);
        if (lane >= o) x += t;
    }
    if (lane < nb) bsum[lane] = x - v;
}

__global__ __launch_bounds__(1024) void scan_add(
    int* __restrict__ off, int* __restrict__ cursor,
    const int* __restrict__ bsum, int N, int E)
{
    int i = blockIdx.x * 1024 + threadIdx.x;
    if (i < N) {
        int o = off[i] + bsum[blockIdx.x];
        off[i] = o; cursor[i] = o;
    }
    if (i == 0) off[N] = E;
}

__global__ __launch_bounds__(256) void scatter_kernel(
    const int* __restrict__ src, const int* __restrict__ dst,
    int* __restrict__ cursor, int* __restrict__ col, int E)
{
    int i = blockIdx.x * 256 + threadIdx.x;
    if (i < E) {
        int pos = atomicAdd(&cursor[dst[i]], 1);
        col[pos] = src[i];
    }
}

// ---------------- gather + residual + LN1 -> xb (bf16), xf (fp32) ----------
__global__ __launch_bounds__(128) void gather_ln1(
    const float* __restrict__ feat, const unsigned* __restrict__ kq,
    const int* __restrict__ off, const int* __restrict__ col,
    const float* __restrict__ ln_g, const float* __restrict__ ln_b,
    unsigned short* __restrict__ xb, float* __restrict__ xf, int N)
{
    __shared__ float sred[2][2];
    const int tid = threadIdx.x;
    const int lane = tid & 63;
    const int wv = tid >> 6;
    const int n0 = blockIdx.x * 8;

    const float gg = ln_g[tid];
    const float bb = ln_b[tid];

    for (int m = 0; m < 8; ++m) {
        int n = n0 + m;
        float xr = 0.f;
        if (n < N) {
            int e0 = off[n], e1 = off[n + 1];
            float d0 = 0.f, q0 = 0.f, d1 = 0.f, q1 = 0.f;
            float d2 = 0.f, q2 = 0.f, d3 = 0.f, q3 = 0.f;
            int e = e0;
            for (; e + 3 < e1; e += 4) {
                unsigned u0 = kq[(size_t)col[e]     * NF + tid];
                unsigned u1 = kq[(size_t)col[e + 1] * NF + tid];
                unsigned u2 = kq[(size_t)col[e + 2] * NF + tid];
                unsigned u3 = kq[(size_t)col[e + 3] * NF + tid];
                d0 += lo_bf(u0); q0 += hi_bf(u0);
                d1 += lo_bf(u1); q1 += hi_bf(u1);
                d2 += lo_bf(u2); q2 += hi_bf(u2);
                d3 += lo_bf(u3); q3 += hi_bf(u3);
            }
            for (; e < e1; ++e) {
                unsigned u = kq[(size_t)col[e] * NF + tid];
                d0 += lo_bf(u); q0 += hi_bf(u);
            }
            d0 += d1 + d2 + d3; q0 += q1 + q2 + q3;
            float ag = (e1 > e0) ? q0 / d0 : 0.f;
            xr = ag + feat[(size_t)n * NF + tid];
        }
        float s1 = xr, s2 = xr * xr;
        #pragma unroll
        for (int o = 32; o > 0; o >>= 1) {
            s1 += __shfl_down(s1, o);
            s2 += __shfl_down(s2, o);
        }
        if (lane == 0) { sred[0][wv] = s1; sred[1][wv] = s2; }
        __syncthreads();
        float mean = (sred[0][0] + sred[0][1]) * (1.f / NF);
        float msq  = (sred[1][0] + sred[1][1]) * (1.f / NF);
        float rs   = rsqrtf(msq - mean * mean + LN_EPS);
        float xv   = (xr - mean) * rs * gg + bb;
        if (n < N) {
            xb[(size_t)n * NF + tid] = f2bf(xv);
            xf[(size_t)n * NF + tid] = xv;
        }
        __syncthreads();
    }
}

// ---------------- fused FFN: GEMM1(MFMA)+PReLU -> GEMM2(MFMA) -> LN2 -------
__global__ __launch_bounds__(256) void ffn_fused(
    const unsigned short* __restrict__ xb, const float* __restrict__ xf,
    const unsigned short* __restrict__ W1f, const unsigned short* __restrict__ W2f,
    const float* __restrict__ b1, const float* __restrict__ alpha,
    const float* __restrict__ b2,
    const float* __restrict__ ln_g, const float* __restrict__ ln_b,
    float* __restrict__ out, int N)
{
    __shared__ unsigned short hlds[4][32][128];  // 32 KB, per-wave slab, XOR-swizzled
    __shared__ float olds[32][NF + 4];

    const int tid = threadIdx.x;
    const int l = tid & 63;
    const int wid = tid >> 6;
    const int l15 = l & 15;
    const int lg = l >> 4;
    const int n0 = blockIdx.x * 32;

    char* hbase = (char*)&hlds[wid][0][0];

    f32x4 acc[2][8];
    #pragma unroll
    for (int mf = 0; mf < 2; ++mf)
        #pragma unroll
        for (int nt = 0; nt < 8; ++nt)
            acc[mf][nt] = (f32x4){0.f, 0.f, 0.f, 0.f};

    #pragma unroll
    for (int kt = 0; kt < 4; ++kt) {
        short8 a0 = *(const short8*)(xb + (size_t)(n0 + l15)      * NF + kt * 32 + lg * 8);
        short8 a1 = *(const short8*)(xb + (size_t)(n0 + 16 + l15) * NF + kt * 32 + lg * 8);
        #pragma unroll
        for (int nt = 0; nt < 8; ++nt) {
            int ntg = wid * 8 + nt;
            short8 b = *(const short8*)(W1f + ((kt * 32 + ntg) * 64 + l) * 8);
            acc[0][nt] = __builtin_amdgcn_mfma_f32_16x16x32_bf16(a0, b, acc[0][nt], 0, 0, 0);
            acc[1][nt] = __builtin_amdgcn_mfma_f32_16x16x32_bf16(a1, b, acc[1][nt], 0, 0, 0);
        }
    }

    #pragma unroll
    for (int nt = 0; nt < 8; ++nt) {
        int jloc = nt * 16 + l15;
        int j = wid * 128 + jloc;
        float b1j = b1[j], alj = alpha[j];
        #pragma unroll
        for (int mf = 0; mf < 2; ++mf) {
            #pragma unroll
            for (int r = 0; r < 4; ++r) {
                int row = mf * 16 + lg * 4 + r;
                float hv = acc[mf][nt][r] + b1j;
                hv = hv > 0.f ? hv : alj * hv;
                int byte = row * 256 + ((jloc * 2) ^ ((row & 7) << 4));
                *(unsigned short*)(hbase + byte) = f2bf(hv);
            }
        }
    }
    __syncthreads();

    f32x4 acc2[2][8];
    #pragma unroll
    for (int mf = 0; mf < 2; ++mf)
        #pragma unroll
        for (int nt = 0; nt < 8; ++nt)
            acc2[mf][nt] = (f32x4){0.f, 0.f, 0.f, 0.f};

    #pragma unroll
    for (int kt = 0; kt < 4; ++kt) {
        int row0 = l15, row1 = 16 + l15;
        int c0 = (kt * 64 + lg * 16) ^ ((row0 & 7) << 4);
        int c1 = (kt * 64 + lg * 16) ^ ((row1 & 7) << 4);
        short8 a0 = *(const short8*)(hbase + row0 * 256 + c0);
        short8 a1 = *(const short8*)(hbase + row1 * 256 + c1);
        int kt2g = wid * 4 + kt;
        #pragma unroll
        for (int nt = 0; nt < 8; ++nt) {
            short8 b = *(const short8*)(W2f + ((kt2g * 8 + nt) * 64 + l) * 8);
            acc2[0][nt] = __builtin_amdgcn_mfma_f32_16x16x32_bf16(a0, b, acc2[0][nt], 0, 0, 0);
            acc2[1][nt] = __builtin_amdgcn_mfma_f32_16x16x32_bf16(a1, b, acc2[1][nt], 0, 0, 0);
        }
    }

    for (int w = 0; w < 4; ++w) {
        if (wid == w) {
            #pragma unroll
            for (int nt = 0; nt < 8; ++nt) {
                int cl = nt * 16 + l15;
                #pragma unroll
                for (int mf = 0; mf < 2; ++mf) {
                    #pragma unroll
                    for (int r = 0; r < 4; ++r) {
                        int row = mf * 16 + lg * 4 + r;
                        if (w == 0) olds[row][cl]  = acc2[mf][nt][r];
                        else        olds[row][cl] += acc2[mf][nt][r];
                    }
                }
            }
        }
        __syncthreads();
    }

    const float gg0 = ln_g[l], gg1 = ln_g[l + 64];
    const float bb0 = ln_b[l], bb1 = ln_b[l + 64];
    const float b20 = b2[l],   b21 = b2[l + 64];
    #pragma unroll
    for (int rr = 0; rr < 8; ++rr) {
        int row = rr * 4 + wid;
        int n = n0 + row;
        float y0 = 0.f, y1 = 0.f;
        if (n < N) {
            y0 = xf[(size_t)n * NF + l]      + olds[row][l]      + b20;
            y1 = xf[(size_t)n * NF + l + 64] + olds[row][l + 64] + b21;
        }
        float s1 = y0 + y1, s2 = y0 * y0 + y1 * y1;
        #pragma unroll
        for (int o = 32; o > 0; o >>= 1) {
            s1 += __shfl_xor(s1, o);
            s2 += __shfl_xor(s2, o);
        }
        float mean = s1 * (1.f / NF);
        float msq  = s2 * (1.f / NF);
        float rs   = rsqrtf(msq - mean * mean + LN_EPS);
        if (n < N) {
            out[(size_t)n * NF + l]      = (y0 - mean) * rs * gg0 + bb0;
            out[(size_t)n * NF + l + 64] = (y1 - mean) * rs * gg1 + bb1;
        }
    }
}

// ---------------------------------------------------------------------------
extern "C" void kernel_launch(void* const* d_in, const int* in_sizes, int n_in,
                              void* d_out, int out_size, void* d_ws, size_t ws_size,
                              hipStream_t stream)
{
    const float* feat  = (const float*)d_in[0];
    const float* Wq    = (const float*)d_in[1];
    const float* Wk    = (const float*)d_in[2];
    // d_in[3] = Wv — cancels in per-channel edge softmax, unused.
    const float* ln_g  = (const float*)d_in[4];
    const float* ln_b  = (const float*)d_in[5];
    const float* W1    = (const float*)d_in[6];
    const float* b1    = (const float*)d_in[7];
    const float* alpha = (const float*)d_in[8];
    const float* W2    = (const float*)d_in[9];
    const float* b2    = (const float*)d_in[10];
    const int*   src   = (const int*)d_in[11];
    const int*   dst   = (const int*)d_in[12];

    const int N = in_sizes[0] / NF;
    const int E = in_sizes[11];
    const int Npad = ((N + 31) / 32) * 32;
    float* out = (float*)d_out;

    char* p = (char*)d_ws;
    unsigned*       kq  = (unsigned*)p;       p += (size_t)N * NF * 4;
    unsigned short* xb  = (unsigned short*)p; p += (size_t)Npad * NF * 2;
    float*          xf  = (float*)p;          p += (size_t)Npad * NF * 4;
    unsigned short* W1f = (unsigned short*)p; p += (size_t)NF * FH * 2;
    unsigned short* W2f = (unsigned short*)p; p += (size_t)FH * NF * 2;
    unsigned short* Wqhi = (unsigned short*)p; p += (size_t)NF * NF * 2;
    unsigned short* Wqlo = (unsigned short*)p; p += (size_t)NF * NF * 2;
    unsigned short* Wkhi = (unsigned short*)p; p += (size_t)NF * NF * 2;
    unsigned short* Wklo = (unsigned short*)p; p += (size_t)NF * NF * 2;
    int* deg    = (int*)p;  p += (size_t)N * 4;
    int* off    = (int*)p;  p += (size_t)(N + 1) * 4;
    int* bsum   = (int*)p;  p += 64 * 4;
    int* cursor = (int*)p;  p += (size_t)N * 4;
    int* col    = (int*)p;

    const int nb = (N + 1023) / 1024;

    hipMemsetAsync(deg, 0, (size_t)N * sizeof(int), stream);

    prep_w<<<256, 256, 0, stream>>>(W1, W2, Wq, Wk, W1f, W2f,
                                    Wqhi, Wqlo, Wkhi, Wklo);
    qk_mfma<<<(N + 31) / 32, 256, 0, stream>>>(feat, Wqhi, Wqlo, Wkhi, Wklo,
                                               kq, N);
    hist_kernel<<<(E + 255) / 256, 256, 0, stream>>>(dst, deg, E);
    scan_blk<<<nb, 1024, 0, stream>>>(deg, off, bsum, N);
    scan_mid<<<1, 64, 0, stream>>>(bsum, nb);
    scan_add<<<nb, 1024, 0, stream>>>(off, cursor, bsum, N, E);
    scatter_kernel<<<(E + 255) / 256, 256, 0, stream>>>(src, dst, cursor, col, E);
    gather_ln1<<<(N + 7) / 8, 128, 0, stream>>>(feat, kq, off, col, ln_g, ln_b,
                                                xb, xf, N);
    ffn_fused<<<(N + 31) / 32, 256, 0, stream>>>(xb, xf, W1f, W2f, b1, alpha,
                                                 b2, ln_g, ln_b, out, N);
}